// Round 9
// baseline (157.259 us; speedup 1.0000x reference)
//
#include <hip/hip_runtime.h>
#include <hip/hip_bf16.h>

typedef __bf16 bf16;
typedef __bf16 bf16x8 __attribute__((ext_vector_type(8)));
typedef float f32x4 __attribute__((ext_vector_type(4)));

#define S_DIM 128
#define L_DIM 512
#define D_DIM 256
#define NQ    1024

// async global->LDS, 16B per lane; lds must be the wave-uniform base
__device__ __forceinline__ void gl16(void* lds, const void* g) {
  __builtin_amdgcn_global_load_lds((const __attribute__((address_space(1))) void*)g,
                                   (__attribute__((address_space(3))) void*)lds,
                                   16, 0, 0);
}

// ---------------- K0: pack weights to bf16, transposed to N-major ----------------
__global__ void pack_weights(const float* __restrict__ wq, const float* __restrict__ wk,
                             const float* __restrict__ wv, const float* __restrict__ wg,
                             const float* __restrict__ wo,
                             bf16* __restrict__ wcat_t, bf16* __restrict__ wo_t) {
  int idx = blockIdx.x * 256 + threadIdx.x;
  const int total1 = NQ * D_DIM; // WcatT [1024][256]
  if (idx < total1) {
    int j = idx >> 8;      // output column 0..1023
    int d = idx & 255;     // k index
    const float* w = (j < 256) ? wq : (j < 512) ? wk : (j < 768) ? wv : wg;
    wcat_t[idx] = (bf16)w[d * 256 + (j & 255)];
  } else {
    int i2 = idx - total1; // woT [256][256]: woT[d][hc] = wo[hc][d]
    if (i2 < D_DIM * D_DIM) {
      int dcol = i2 >> 8, k = i2 & 255;
      wo_t[i2] = (bf16)wo[k * 256 + dcol];
    }
  }
}

// ---------------- K1: LayerNorm, one wave per row, coalesced bf16 write -----------
// x_ln row = s*512 + l (same index as msa row).
__global__ __launch_bounds__(256) void ln_kernel(const float* __restrict__ x,
                                                 const float* __restrict__ sc,
                                                 const float* __restrict__ bs,
                                                 bf16* __restrict__ y) {
  int wid  = threadIdx.x >> 6;
  int lane = threadIdx.x & 63;
  int row  = blockIdx.x * 4 + wid;
  float4 v = ((const float4*)(x + (size_t)row * D_DIM))[lane];
  float s = v.x + v.y + v.z + v.w;
  #pragma unroll
  for (int m = 32; m; m >>= 1) s += __shfl_xor(s, m);
  float mu = s * (1.0f / 256.0f);
  float dx = v.x - mu, dy = v.y - mu, dz = v.z - mu, dw = v.w - mu;
  float s2 = dx * dx + dy * dy + dz * dz + dw * dw;
  #pragma unroll
  for (int m = 32; m; m >>= 1) s2 += __shfl_xor(s2, m);
  float rs = rsqrtf(s2 * (1.0f / 256.0f) + 1e-5f);
  float4 scv = ((const float4*)sc)[lane];
  float4 bsv = ((const float4*)bs)[lane];
  union { uint2 u; bf16 b[4]; } o;
  o.b[0] = (bf16)(dx * rs * scv.x + bsv.x);
  o.b[1] = (bf16)(dy * rs * scv.y + bsv.y);
  o.b[2] = (bf16)(dz * rs * scv.z + bsv.z);
  o.b[3] = (bf16)(dw * rs * scv.w + bsv.w);
  ((uint2*)y)[(size_t)row * 64 + lane] = o.u;
}

// swizzled LDS fragment read: logical (row, k-elem) in a [*][64] bf16 tile,
// physical byte = (row*128 + k*2) ^ ((row&7)<<4)
__device__ __forceinline__ bf16x8 lds_swz(const bf16* base, int row, int k) {
  return *(const bf16x8*)((const char*)base + ((((row << 6) + k) << 1) ^ ((row & 7) << 4)));
}

// ---------------- K2: QKVG GEMM -> attention-native panels (R6-measured) ----------
// A = x_ln[65536][256] (row = s*512+l) @ WcatT[1024][256] ->
// pan[type][res][hpair][128 s][64 c] bf16. m-tile = fixed s, 128 res.
// 128x128 tile, BK=64, gl16 pre-swizzled staging (conflict-free ds_read_b128),
// XCD-grouped blocks, LDS-transpose epilogue, sigmoid on gate cols.
__global__ __launch_bounds__(256, 4) void gemm_qkvg(const bf16* __restrict__ A,
                                                    const bf16* __restrict__ Bt,
                                                    bf16* __restrict__ pan,
                                                    const float* __restrict__ bias) {
  __shared__ __align__(16) bf16 smem[16384];   // As|Bs; reused as C-stage
  bf16* As = smem;
  bf16* Bs = smem + 8192;
  const int tid  = threadIdx.x;
  const int wid  = tid >> 6;
  const int lane = tid & 63;
  const int bid   = blockIdx.x;
  const int n_idx = (bid >> 3) & 7;
  const int m_idx = (bid & 7) | ((bid >> 6) << 3);
  const int m0 = m_idx * 128;
  const int n0 = n_idx * 128;
  const int lrow = lane & 15;
  const int lk   = (lane >> 4) * 8;
  const int wr = wid >> 1, wc = wid & 1;

  const int ln8 = lane >> 3;
  const int c8  = ((lane & 7) ^ ln8) * 8;       // pre-swizzled source 16B slot

  const bf16* Arow = A  + (size_t)m0 * 256 + c8;
  const bf16* Brow = Bt + (size_t)n0 * 256 + c8;

  f32x4 acc[4][4] = {};

  #pragma unroll
  for (int ks = 0; ks < 4; ++ks) {
    const int k0 = ks * 64;
    #pragma unroll
    for (int t = 0; t < 4; ++t) {
      int chunk = wid * 4 + t;
      int r = chunk * 8 + ln8;
      gl16(&As[chunk * 512], Arow + (size_t)r * 256 + k0);
      gl16(&Bs[chunk * 512], Brow + (size_t)r * 256 + k0);
    }
    __syncthreads();
    #pragma unroll
    for (int kk = 0; kk < 64; kk += 32) {
      bf16x8 av[4], bv[4];
      #pragma unroll
      for (int i = 0; i < 4; ++i)
        av[i] = lds_swz(As, wr * 64 + i * 16 + lrow, kk + lk);
      #pragma unroll
      for (int j = 0; j < 4; ++j)
        bv[j] = lds_swz(Bs, wc * 64 + j * 16 + lrow, kk + lk);
      #pragma unroll
      for (int i = 0; i < 4; ++i)
        #pragma unroll
        for (int j = 0; j < 4; ++j)
          acc[i][j] = __builtin_amdgcn_mfma_f32_16x16x32_bf16(av[i], bv[j], acc[i][j], 0, 0, 0);
    }
    __syncthreads();
  }

  const int rb = (lane >> 4) * 4;
  const int xorv = rb << 2;

  const bool isg = (n_idx >= 6);                // type 3 = gate
  float bgv[4];
  if (isg) {
    #pragma unroll
    for (int j = 0; j < 4; ++j) bgv[j] = bias[(n_idx & 1) * 128 + wc * 64 + j * 16 + lrow];
  }
  #pragma unroll
  for (int i = 0; i < 4; ++i)
    #pragma unroll
    for (int j = 0; j < 4; ++j) {
      int col = wc * 64 + j * 16 + lrow;
      #pragma unroll
      for (int r = 0; r < 4; ++r) {
        int row = wr * 64 + i * 16 + rb + r;
        float v = acc[i][j][r];
        if (isg) { v += bgv[j]; v = 1.0f / (1.0f + __expf(-v)); }
        smem[row * 128 + (col ^ xorv)] = (bf16)v;
      }
    }
  __syncthreads();

  // panel store: tile = fixed s, res0..res0+127, type, hpairs hp0,hp0+1
  const int type = n_idx >> 1;
  const int hp0  = (n_idx & 1) * 2;
  const int s    = m_idx >> 2;
  const int res0 = (m_idx & 3) * 128;
  #pragma unroll
  for (int p = 0; p < 8; ++p) {
    int ch = p * 256 + tid;
    int c16 = ch & 7, hpl = (ch >> 3) & 1, rr = ch >> 4;
    int col = hpl * 64 + c16 * 8;
    *(uint4*)(pan + ((size_t)((type * 512 + res0 + rr) * 4) + hp0 + hpl) * 8192 + s * 64 + c16 * 8) =
        *(const uint4*)(smem + rr * 128 + (col ^ ((rr & 12) << 2)));
  }
}

// ---------------- K3: fused attention + gate + output projection, per residue ------
// Block = residue (512 blocks), 512 threads, wave = head. Zero barriers in attention.
// Raw O -> shared o_full; gate fused into proj A-frag build from g-panels.
__global__ __launch_bounds__(512, 2) void attn_proj(const bf16* __restrict__ pan,
                                                    const bf16* __restrict__ wo_t,
                                                    const float* __restrict__ bo,
                                                    float* __restrict__ out) {
  // vt 8x[32][136] (69632) | pwb 8x[16][72] (18432) | o_full [128][264] (67584) = 155648
  // overlays after attn barrier: wS 64K at 0; fb [32][264] f32 (33792) at 0 in epilogue
  __shared__ __align__(16) char smem[155648];
  const int tid  = threadIdx.x;
  const int wid  = tid >> 6;
  const int lane = tid & 63;
  const int lrow = lane & 15;
  const int lkg  = lane >> 4;
  const int lk   = lkg * 8;
  const int rb   = lkg * 4;
  const int res  = blockIdx.x;
  const int h    = wid;
  const int hp   = h >> 1;
  const int hl   = (h & 1) * 32;

  bf16* vw  = (bf16*)(smem + wid * 8704);
  bf16* pwb = (bf16*)(smem + 69632 + wid * 2304);
  bf16* of  = (bf16*)(smem + 88064);

  const bf16* Pq = pan + ((size_t)((0 * 512 + res) * 4) + hp) * 8192 + hl;
  const bf16* Pk = pan + ((size_t)((1 * 512 + res) * 4) + hp) * 8192 + hl;
  const bf16* Pv = pan + ((size_t)((2 * 512 + res) * 4) + hp) * 8192 + hl;

  // stage V^T (wave-private)
  {
    int t0 = lane >> 2, cs = (lane & 3) * 8;
    #pragma unroll
    for (int p = 0; p < 8; ++p) {
      int t = p * 16 + t0;
      union { uint4 u; bf16 e[8]; } v;
      v.u = *(const uint4*)(Pv + t * 64 + cs);
      #pragma unroll
      for (int j = 0; j < 8; ++j) vw[(cs + j) * 136 + t] = v.e[j];
    }
  }

  // K fragments in registers
  bf16x8 kf[8];
  #pragma unroll
  for (int tt = 0; tt < 8; ++tt)
    kf[tt] = *(const bf16x8*)(Pk + (tt * 16 + lrow) * 64 + lk);

  const float scale = 0.17677669529663687f; // 1/sqrt(32)
  const f32x4 z = {0.f, 0.f, 0.f, 0.f};

  for (int st = 0; st < 8; ++st) {
    bf16x8 qf = *(const bf16x8*)(Pq + (st * 16 + lrow) * 64 + lk);
    f32x4 sc[8];
    #pragma unroll
    for (int tt = 0; tt < 8; ++tt)
      sc[tt] = __builtin_amdgcn_mfma_f32_16x16x32_bf16(qf, kf[tt], z, 0, 0, 0);

    #pragma unroll
    for (int r = 0; r < 4; ++r) {
      float m = sc[0][r];
      #pragma unroll
      for (int tc = 1; tc < 8; ++tc) m = fmaxf(m, sc[tc][r]);
      #pragma unroll
      for (int msk = 8; msk; msk >>= 1) m = fmaxf(m, __shfl_xor(m, msk));
      float pv[8], ssum = 0.f;
      #pragma unroll
      for (int tc = 0; tc < 8; ++tc) {
        float p = __expf((sc[tc][r] - m) * scale);
        pv[tc] = p; ssum += p;
      }
      #pragma unroll
      for (int msk = 8; msk; msk >>= 1) ssum += __shfl_xor(ssum, msk);
      float inv = 1.0f / ssum;
      #pragma unroll
      for (int tc = 0; tc < 8; ++tc) sc[tc][r] = pv[tc] * inv;
    }

    // PV through wave-private transpose buffer (two t-halves)
    f32x4 oc[2] = {z, z};
    #pragma unroll
    for (int hf = 0; hf < 2; ++hf) {
      #pragma unroll
      for (int tc = 0; tc < 4; ++tc)
        #pragma unroll
        for (int r = 0; r < 4; ++r)
          pwb[(rb + r) * 72 + tc * 16 + lrow] = (bf16)sc[hf * 4 + tc][r];
      #pragma unroll
      for (int kc = 0; kc < 2; ++kc) {
        bf16x8 pa = *(const bf16x8*)(pwb + lrow * 72 + kc * 32 + lk);
        #pragma unroll
        for (int ct = 0; ct < 2; ++ct) {
          bf16x8 bv = *(const bf16x8*)(vw + (ct * 16 + lrow) * 136 + hf * 64 + kc * 32 + lk);
          oc[ct] = __builtin_amdgcn_mfma_f32_16x16x32_bf16(pa, bv, oc[ct], 0, 0, 0);
        }
      }
    }
    // raw O strip -> o_full (own head's 32 cols)
    #pragma unroll
    for (int ct = 0; ct < 2; ++ct)
      #pragma unroll
      for (int r = 0; r < 4; ++r)
        of[(st * 16 + rb + r) * 264 + h * 32 + ct * 16 + lrow] = (bf16)oc[ct][r];
  }
  __syncthreads();   // o_full complete; vt/pwb dead

  // ---- projection: out = (o*g)[128][256] @ woT^T + bo ----
  const int wm = wid >> 1;   // band (32 rows)
  const int pn = wid & 1;    // 64-col group per 128-half

  bf16x8 af[2][8];
  #pragma unroll
  for (int mt = 0; mt < 2; ++mt) {
    int s = wm * 32 + mt * 16 + lrow;
    #pragma unroll
    for (int kt = 0; kt < 8; ++kt) {
      bf16x8 o8 = *(const bf16x8*)(of + s * 264 + kt * 32 + lk);
      bf16x8 g8 = *(const bf16x8*)(pan + ((size_t)((3 * 512 + res) * 4) + (kt >> 1)) * 8192 +
                                   (kt & 1) * 32 + s * 64 + lk);
      bf16x8 rr;
      #pragma unroll
      for (int j = 0; j < 8; ++j) rr[j] = (bf16)((float)o8[j] * (float)g8[j]);
      af[mt][kt] = rr;
    }
  }

  float bov[2][4];
  #pragma unroll
  for (int hf = 0; hf < 2; ++hf)
    #pragma unroll
    for (int nt = 0; nt < 4; ++nt)
      bov[hf][nt] = bo[hf * 128 + pn * 64 + nt * 16 + lrow];

  bf16* wS = (bf16*)smem;
  f32x4 acc[2][2][4] = {};   // [half][mt][nt]
  #pragma unroll
  for (int hf = 0; hf < 2; ++hf) {
    #pragma unroll
    for (int p = 0; p < 8; ++p) {
      int ch = p * 512 + tid;
      int dl = ch >> 5, sl = ch & 31;
      gl16((char*)wS + p * 8192 + wid * 1024,
           (const char*)wo_t + (size_t)(hf * 128 + dl) * 512 + (((sl * 16) ^ ((dl & 7) << 4))));
    }
    __syncthreads();
    #pragma unroll
    for (int kt = 0; kt < 8; ++kt)
      #pragma unroll
      for (int nt = 0; nt < 4; ++nt) {
        int dl = pn * 64 + nt * 16 + lrow;
        bf16x8 bw = *(const bf16x8*)((char*)wS + dl * 512 + (((kt * 4 + lkg) ^ (dl & 7)) << 4));
        acc[hf][0][nt] = __builtin_amdgcn_mfma_f32_16x16x32_bf16(af[0][kt], bw, acc[hf][0][nt], 0, 0, 0);
        acc[hf][1][nt] = __builtin_amdgcn_mfma_f32_16x16x32_bf16(af[1][kt], bw, acc[hf][1][nt], 0, 0, 0);
      }
    __syncthreads();   // wS reads done before overwrite
  }

  // epilogue: 4 bands of 32 rows via f32 LDS, full-line coalesced stores
  float* fb = (float*)smem;
  #pragma unroll 1
  for (int b = 0; b < 4; ++b) {
    if (wm == b) {
      #pragma unroll
      for (int hf = 0; hf < 2; ++hf)
        #pragma unroll
        for (int mt = 0; mt < 2; ++mt)
          #pragma unroll
          for (int nt = 0; nt < 4; ++nt)
            #pragma unroll
            for (int r = 0; r < 4; ++r)
              fb[(mt * 16 + rb + r) * 264 + hf * 128 + pn * 64 + nt * 16 + lrow] =
                  acc[hf][mt][nt][r] + bov[hf][nt];
    }
    __syncthreads();
    #pragma unroll
    for (int u = 0; u < 4; ++u) {
      int ch = u * 512 + tid;
      int row = ch >> 6, c4 = (ch & 63) * 4;
      *(uint4*)(out + ((size_t)(b * 32 + row) * L_DIM + res) * 256 + c4) =
          *(const uint4*)(fb + row * 264 + c4);
    }
    __syncthreads();
  }
}

// ---------------- launch ----------------
extern "C" void kernel_launch(void* const* d_in, const int* in_sizes, int n_in,
                              void* d_out, int out_size, void* d_ws, size_t ws_size,
                              hipStream_t stream) {
  const float* msa      = (const float*)d_in[0];
  const float* ln_scale = (const float*)d_in[1];
  const float* ln_bias  = (const float*)d_in[2];
  const float* wq       = (const float*)d_in[3];
  const float* wk       = (const float*)d_in[4];
  const float* wv       = (const float*)d_in[5];
  const float* wg       = (const float*)d_in[6];
  const float* bg       = (const float*)d_in[7];
  const float* wo       = (const float*)d_in[8];
  const float* bo       = (const float*)d_in[9];
  float* out = (float*)d_out;

  char* ws = (char*)d_ws;
  bf16* wcat_t = (bf16*)ws;                                  // 512 KB
  bf16* wo_t   = (bf16*)(ws + 524288);                       // 128 KB
  bf16* pan    = (bf16*)(ws + 655360);                       // 128 MB panels
  bf16* x_ln   = (bf16*)d_out;                               // 32 MB scratch in d_out (dead before attn_proj writes)

  pack_weights<<<dim3(1280), dim3(256), 0, stream>>>(wq, wk, wv, wg, wo, wcat_t, wo_t);
  ln_kernel<<<dim3(65536 / 4), dim3(256), 0, stream>>>(msa, ln_scale, ln_bias, x_ln);
  gemm_qkvg<<<dim3(4096), dim3(256), 0, stream>>>(x_ln, wcat_t, pan, bg);
  attn_proj<<<dim3(512), dim3(512), 0, stream>>>(pan, wo_t, bo, out);
}

// Round 10
// 138.775 us; speedup vs baseline: 1.1332x; 1.1332x over previous
//
#include <hip/hip_runtime.h>
#include <hip/hip_bf16.h>

typedef __bf16 bf16;
typedef __bf16 bf16x8 __attribute__((ext_vector_type(8)));
typedef float f32x4 __attribute__((ext_vector_type(4)));

#define S_DIM 128
#define L_DIM 512
#define D_DIM 256
#define NQ    1024

// async global->LDS, 16B per lane; lds must be the wave-uniform base
__device__ __forceinline__ void gl16(void* lds, const void* g) {
  __builtin_amdgcn_global_load_lds((const __attribute__((address_space(1))) void*)g,
                                   (__attribute__((address_space(3))) void*)lds,
                                   16, 0, 0);
}

// ---------------- K0: pack weights to bf16, transposed to N-major ----------------
__global__ void pack_weights(const float* __restrict__ wq, const float* __restrict__ wk,
                             const float* __restrict__ wv, const float* __restrict__ wg,
                             const float* __restrict__ wo,
                             bf16* __restrict__ wcat_t, bf16* __restrict__ wo_t) {
  int idx = blockIdx.x * 256 + threadIdx.x;
  const int total1 = NQ * D_DIM; // WcatT [1024][256]
  if (idx < total1) {
    int j = idx >> 8;      // output column 0..1023
    int d = idx & 255;     // k index
    const float* w = (j < 256) ? wq : (j < 512) ? wk : (j < 768) ? wv : wg;
    wcat_t[idx] = (bf16)w[d * 256 + (j & 255)];
  } else {
    int i2 = idx - total1; // woT [256][256]: woT[d][hc] = wo[hc][d]
    if (i2 < D_DIM * D_DIM) {
      int dcol = i2 >> 8, k = i2 & 255;
      wo_t[i2] = (bf16)wo[k * 256 + dcol];
    }
  }
}

// ---------------- K1: fused LayerNorm + QKVG GEMM -> panels, per residue ----------
// Block = residue (512 blocks), 512 threads (8 waves), LDS 80 KB -> 2 blocks/CU.
// Phase A: LN of msa[s][res][:] -> swizzled A-LDS [128 s][256 k] bf16 (64 KB).
// Then A-frags cached in regs; A-LDS region REUSED as B double-buffer (2x32 KB).
// N-loop: 16 chunks of 64 cols; dense 16 KB panel store per chunk.
// pan[type][res][hpair][128 s][64 c] bf16 (type 0..3 = q,k,v,g).
__global__ __launch_bounds__(512, 4) void ln_qkvg(const float* __restrict__ msa,
                                                  const float* __restrict__ lns,
                                                  const float* __restrict__ lnb,
                                                  const bf16* __restrict__ wcat,
                                                  const float* __restrict__ bg,
                                                  bf16* __restrict__ pan) {
  __shared__ __align__(16) char smem[81920];   // [0,64K): A, then B dbuf; [64K,80K): Cst
  bf16* Albs = (bf16*)smem;
  char* Bb   = smem;
  bf16* Cst  = (bf16*)(smem + 65536);
  const int tid  = threadIdx.x;
  const int wid  = tid >> 6;
  const int lane = tid & 63;
  const int lrow = lane & 15;
  const int lkg  = lane >> 4;
  const int lk   = lkg * 8;
  const int rb   = lkg * 4;
  const int res  = blockIdx.x;

  // ---- Phase A: LayerNorm, wave handles rows s = wid*16 .. +15 ----
  {
    float4 scv = ((const float4*)lns)[lane];
    float4 bsv = ((const float4*)lnb)[lane];
    const float* mbase = msa + ((size_t)(wid * 16) * 512 + res) * 256 + lane * 4;
    #pragma unroll
    for (int b4 = 0; b4 < 4; ++b4) {
      float4 rv[4];
      #pragma unroll
      for (int i = 0; i < 4; ++i)
        rv[i] = *(const float4*)(mbase + (size_t)(b4 * 4 + i) * 512 * 256);
      #pragma unroll
      for (int i = 0; i < 4; ++i) {
        int s = wid * 16 + b4 * 4 + i;
        float4 v = rv[i];
        float sum = v.x + v.y + v.z + v.w;
        #pragma unroll
        for (int m = 32; m; m >>= 1) sum += __shfl_xor(sum, m);
        float mu = sum * (1.0f / 256.0f);
        float dx = v.x - mu, dy = v.y - mu, dz = v.z - mu, dw = v.w - mu;
        float s2 = dx * dx + dy * dy + dz * dz + dw * dw;
        #pragma unroll
        for (int m = 32; m; m >>= 1) s2 += __shfl_xor(s2, m);
        float rs = rsqrtf(s2 * (1.0f / 256.0f) + 1e-5f);
        union { uint2 u; bf16 b[4]; } o;
        o.b[0] = (bf16)(dx * rs * scv.x + bsv.x);
        o.b[1] = (bf16)(dy * rs * scv.y + bsv.y);
        o.b[2] = (bf16)(dz * rs * scv.z + bsv.z);
        o.b[3] = (bf16)(dw * rs * scv.w + bsv.w);
        *(uint2*)((char*)Albs + (((s * 512) + lane * 8) ^ ((s & 7) << 4))) = o.u;
      }
    }
  }
  __syncthreads();   // A-LDS complete

  // ---- cache A-fragments in registers; wave role: mq rows, nh col-half ----
  const int mq = wid & 3;
  const int nh = wid >> 2;
  bf16x8 afc[2][8];
  #pragma unroll
  for (int mt = 0; mt < 2; ++mt)
    #pragma unroll
    for (int kk = 0; kk < 8; ++kk) {
      int row = mq * 32 + mt * 16 + lrow;
      afc[mt][kk] = *(const bf16x8*)((char*)Albs +
                      (((row * 512) + (kk * 32 + lk) * 2) ^ ((row & 7) << 4)));
    }
  __syncthreads();   // all afc reads done; A region free for B staging

  // stage chunk 0 (cols 0..63) into Bb half 0: 64 rows x 512 B, pre-swizzled source
  #pragma unroll
  for (int p = 0; p < 4; ++p) {
    int ch = p * 512 + tid;
    int n = ch >> 5;
    int inner = (ch & 31) * 16;
    gl16(Bb + p * 8192 + wid * 1024,
         (const char*)wcat + (size_t)n * 512 + (inner ^ ((n & 7) << 4)));
  }
  __syncthreads();   // chunk0 landed

  for (int cc = 0; cc < 16; ++cc) {
    char* Bcur = Bb + (cc & 1) * 32768;
    // compute: 32 MFMA/wave from Bcur
    f32x4 acc[2][2] = {};
    #pragma unroll
    for (int kk = 0; kk < 8; ++kk) {
      bf16x8 bv[2];
      #pragma unroll
      for (int nt = 0; nt < 2; ++nt) {
        int nl = nh * 32 + nt * 16 + lrow;
        bv[nt] = *(const bf16x8*)(Bcur +
                    (((nl * 512) + (kk * 32 + lk) * 2) ^ ((nl & 7) << 4)));
      }
      #pragma unroll
      for (int mt = 0; mt < 2; ++mt)
        #pragma unroll
        for (int nt = 0; nt < 2; ++nt)
          acc[mt][nt] = __builtin_amdgcn_mfma_f32_16x16x32_bf16(afc[mt][kk], bv[nt], acc[mt][nt], 0, 0, 0);
    }
    // issue next chunk stage (hidden under epilogue VALU)
    if (cc < 15) {
      char* Bnxt = Bb + ((cc + 1) & 1) * 32768;
      const size_t ncol0 = (size_t)(cc + 1) * 64;
      #pragma unroll
      for (int p = 0; p < 4; ++p) {
        int ch = p * 512 + tid;
        int n = ch >> 5;
        int inner = (ch & 31) * 16;
        gl16(Bnxt + p * 8192 + wid * 1024,
             (const char*)wcat + (ncol0 + n) * 512 + (inner ^ ((n & 7) << 4)));
      }
    }
    // epilogue -> Cst (granule XOR)
    const bool isg = (cc >= 12);
    #pragma unroll
    for (int mt = 0; mt < 2; ++mt)
      #pragma unroll
      for (int nt = 0; nt < 2; ++nt) {
        int col = nh * 32 + nt * 16 + lrow;
        float bgv = isg ? bg[(cc - 12) * 64 + col] : 0.f;
        #pragma unroll
        for (int r = 0; r < 4; ++r) {
          int row = mq * 32 + mt * 16 + rb + r;
          float v = acc[mt][nt][r];
          if (isg) { v += bgv; v = 1.0f / (1.0f + __expf(-v)); }
          Cst[row * 64 + (col ^ (rb << 2))] = (bf16)v;
        }
      }
    __syncthreads();   // Cst complete; Bcur reads done; (also drains Bnxt stage)
    // dense panel store (16 KB)
    {
      const int type = cc >> 2, hp = cc & 3;
      bf16* pbase = pan + ((size_t)((type * 512 + res) * 4) + hp) * 8192;
      #pragma unroll
      for (int p = 0; p < 2; ++p) {
        int ch = p * 512 + tid;
        int rr = ch >> 3, c16 = ch & 7;
        *(uint4*)(pbase + rr * 64 + c16 * 8) =
            *(const uint4*)(Cst + rr * 64 + ((c16 * 8) ^ ((rr & 12) << 2)));
      }
    }
    // lgkm-only barrier: Cst LDS-reads done before next epilogue overwrites;
    // panel global stores keep draining under next chunk's compute.
    asm volatile("s_waitcnt lgkmcnt(0)" ::: "memory");
    __builtin_amdgcn_s_barrier();
  }
}

// ---------------- K2: fused attention + gate + output projection, per residue ------
// Block = residue (512 blocks), 512 threads, wave = head. Zero barriers in attention.
// Raw O -> shared o_full; gate fused into proj A-frag build from g-panels.
__global__ __launch_bounds__(512, 2) void attn_proj(const bf16* __restrict__ pan,
                                                    const bf16* __restrict__ wo_t,
                                                    const float* __restrict__ bo,
                                                    float* __restrict__ out) {
  // vt 8x[32][136] (69632) | pwb 8x[16][72] (18432) | o_full [128][264] (67584) = 155648
  // overlays after attn barrier: wS 64K at 0; fb [32][264] f32 (33792) at 0 in epilogue
  __shared__ __align__(16) char smem[155648];
  const int tid  = threadIdx.x;
  const int wid  = tid >> 6;
  const int lane = tid & 63;
  const int lrow = lane & 15;
  const int lkg  = lane >> 4;
  const int lk   = lkg * 8;
  const int rb   = lkg * 4;
  const int res  = blockIdx.x;
  const int h    = wid;
  const int hp   = h >> 1;
  const int hl   = (h & 1) * 32;

  bf16* vw  = (bf16*)(smem + wid * 8704);
  bf16* pwb = (bf16*)(smem + 69632 + wid * 2304);
  bf16* of  = (bf16*)(smem + 88064);

  const bf16* Pq = pan + ((size_t)((0 * 512 + res) * 4) + hp) * 8192 + hl;
  const bf16* Pk = pan + ((size_t)((1 * 512 + res) * 4) + hp) * 8192 + hl;
  const bf16* Pv = pan + ((size_t)((2 * 512 + res) * 4) + hp) * 8192 + hl;

  // stage V^T (wave-private)
  {
    int t0 = lane >> 2, cs = (lane & 3) * 8;
    #pragma unroll
    for (int p = 0; p < 8; ++p) {
      int t = p * 16 + t0;
      union { uint4 u; bf16 e[8]; } v;
      v.u = *(const uint4*)(Pv + t * 64 + cs);
      #pragma unroll
      for (int j = 0; j < 8; ++j) vw[(cs + j) * 136 + t] = v.e[j];
    }
  }

  // K fragments in registers
  bf16x8 kf[8];
  #pragma unroll
  for (int tt = 0; tt < 8; ++tt)
    kf[tt] = *(const bf16x8*)(Pk + (tt * 16 + lrow) * 64 + lk);

  const float scale = 0.17677669529663687f; // 1/sqrt(32)
  const f32x4 z = {0.f, 0.f, 0.f, 0.f};

  for (int st = 0; st < 8; ++st) {
    bf16x8 qf = *(const bf16x8*)(Pq + (st * 16 + lrow) * 64 + lk);
    f32x4 sc[8];
    #pragma unroll
    for (int tt = 0; tt < 8; ++tt)
      sc[tt] = __builtin_amdgcn_mfma_f32_16x16x32_bf16(qf, kf[tt], z, 0, 0, 0);

    #pragma unroll
    for (int r = 0; r < 4; ++r) {
      float m = sc[0][r];
      #pragma unroll
      for (int tc = 1; tc < 8; ++tc) m = fmaxf(m, sc[tc][r]);
      #pragma unroll
      for (int msk = 8; msk; msk >>= 1) m = fmaxf(m, __shfl_xor(m, msk));
      float pv[8], ssum = 0.f;
      #pragma unroll
      for (int tc = 0; tc < 8; ++tc) {
        float p = __expf((sc[tc][r] - m) * scale);
        pv[tc] = p; ssum += p;
      }
      #pragma unroll
      for (int msk = 8; msk; msk >>= 1) ssum += __shfl_xor(ssum, msk);
      float inv = 1.0f / ssum;
      #pragma unroll
      for (int tc = 0; tc < 8; ++tc) sc[tc][r] = pv[tc] * inv;
    }

    // PV through wave-private transpose buffer (two t-halves)
    f32x4 oc[2] = {z, z};
    #pragma unroll
    for (int hf = 0; hf < 2; ++hf) {
      #pragma unroll
      for (int tc = 0; tc < 4; ++tc)
        #pragma unroll
        for (int r = 0; r < 4; ++r)
          pwb[(rb + r) * 72 + tc * 16 + lrow] = (bf16)sc[hf * 4 + tc][r];
      #pragma unroll
      for (int kc = 0; kc < 2; ++kc) {
        bf16x8 pa = *(const bf16x8*)(pwb + lrow * 72 + kc * 32 + lk);
        #pragma unroll
        for (int ct = 0; ct < 2; ++ct) {
          bf16x8 bv = *(const bf16x8*)(vw + (ct * 16 + lrow) * 136 + hf * 64 + kc * 32 + lk);
          oc[ct] = __builtin_amdgcn_mfma_f32_16x16x32_bf16(pa, bv, oc[ct], 0, 0, 0);
        }
      }
    }
    // raw O strip -> o_full (own head's 32 cols)
    #pragma unroll
    for (int ct = 0; ct < 2; ++ct)
      #pragma unroll
      for (int r = 0; r < 4; ++r)
        of[(st * 16 + rb + r) * 264 + h * 32 + ct * 16 + lrow] = (bf16)oc[ct][r];
  }
  __syncthreads();   // o_full complete; vt/pwb dead

  // ---- projection: out = (o*g)[128][256] @ woT^T + bo ----
  const int wm = wid >> 1;   // band (32 rows)
  const int pn = wid & 1;    // 64-col group per 128-half

  bf16x8 af[2][8];
  #pragma unroll
  for (int mt = 0; mt < 2; ++mt) {
    int s = wm * 32 + mt * 16 + lrow;
    #pragma unroll
    for (int kt = 0; kt < 8; ++kt) {
      bf16x8 o8 = *(const bf16x8*)(of + s * 264 + kt * 32 + lk);
      bf16x8 g8 = *(const bf16x8*)(pan + ((size_t)((3 * 512 + res) * 4) + (kt >> 1)) * 8192 +
                                   (kt & 1) * 32 + s * 64 + lk);
      bf16x8 rr;
      #pragma unroll
      for (int j = 0; j < 8; ++j) rr[j] = (bf16)((float)o8[j] * (float)g8[j]);
      af[mt][kt] = rr;
    }
  }

  float bov[2][4];
  #pragma unroll
  for (int hf = 0; hf < 2; ++hf)
    #pragma unroll
    for (int nt = 0; nt < 4; ++nt)
      bov[hf][nt] = bo[hf * 128 + pn * 64 + nt * 16 + lrow];

  bf16* wS = (bf16*)smem;
  f32x4 acc[2][2][4] = {};   // [half][mt][nt]
  #pragma unroll
  for (int hf = 0; hf < 2; ++hf) {
    #pragma unroll
    for (int p = 0; p < 8; ++p) {
      int ch = p * 512 + tid;
      int dl = ch >> 5, sl = ch & 31;
      gl16((char*)wS + p * 8192 + wid * 1024,
           (const char*)wo_t + (size_t)(hf * 128 + dl) * 512 + (((sl * 16) ^ ((dl & 7) << 4))));
    }
    __syncthreads();
    #pragma unroll
    for (int kt = 0; kt < 8; ++kt)
      #pragma unroll
      for (int nt = 0; nt < 4; ++nt) {
        int dl = pn * 64 + nt * 16 + lrow;
        bf16x8 bw = *(const bf16x8*)((char*)wS + dl * 512 + (((kt * 4 + lkg) ^ (dl & 7)) << 4));
        acc[hf][0][nt] = __builtin_amdgcn_mfma_f32_16x16x32_bf16(af[0][kt], bw, acc[hf][0][nt], 0, 0, 0);
        acc[hf][1][nt] = __builtin_amdgcn_mfma_f32_16x16x32_bf16(af[1][kt], bw, acc[hf][1][nt], 0, 0, 0);
      }
    __syncthreads();   // wS reads done before overwrite
  }

  // epilogue: 4 bands of 32 rows via f32 LDS, full-line coalesced stores
  float* fb = (float*)smem;
  #pragma unroll 1
  for (int b = 0; b < 4; ++b) {
    if (wm == b) {
      #pragma unroll
      for (int hf = 0; hf < 2; ++hf)
        #pragma unroll
        for (int mt = 0; mt < 2; ++mt)
          #pragma unroll
          for (int nt = 0; nt < 4; ++nt)
            #pragma unroll
            for (int r = 0; r < 4; ++r)
              fb[(mt * 16 + rb + r) * 264 + hf * 128 + pn * 64 + nt * 16 + lrow] =
                  acc[hf][mt][nt][r] + bov[hf][nt];
    }
    __syncthreads();
    #pragma unroll
    for (int u = 0; u < 4; ++u) {
      int ch = u * 512 + tid;
      int row = ch >> 6, c4 = (ch & 63) * 4;
      *(uint4*)(out + ((size_t)(b * 32 + row) * L_DIM + res) * 256 + c4) =
          *(const uint4*)(fb + row * 264 + c4);
    }
    __syncthreads();
  }
}

// ---------------- launch ----------------
extern "C" void kernel_launch(void* const* d_in, const int* in_sizes, int n_in,
                              void* d_out, int out_size, void* d_ws, size_t ws_size,
                              hipStream_t stream) {
  const float* msa      = (const float*)d_in[0];
  const float* ln_scale = (const float*)d_in[1];
  const float* ln_bias  = (const float*)d_in[2];
  const float* wq       = (const float*)d_in[3];
  const float* wk       = (const float*)d_in[4];
  const float* wv       = (const float*)d_in[5];
  const float* wg       = (const float*)d_in[6];
  const float* bg       = (const float*)d_in[7];
  const float* wo       = (const float*)d_in[8];
  const float* bo       = (const float*)d_in[9];
  float* out = (float*)d_out;

  char* ws = (char*)d_ws;
  bf16* wcat_t = (bf16*)ws;                                  // 512 KB
  bf16* wo_t   = (bf16*)(ws + 524288);                       // 128 KB
  bf16* pan    = (bf16*)(ws + 655360);                       // 128 MB panels

  pack_weights<<<dim3(1280), dim3(256), 0, stream>>>(wq, wk, wv, wg, wo, wcat_t, wo_t);
  ln_qkvg<<<dim3(512), dim3(512), 0, stream>>>(msa, ln_scale, ln_bias, wcat_t, bg, pan);
  attn_proj<<<dim3(512), dim3(512), 0, stream>>>(pan, wo_t, bo, out);
}